// Round 16
// baseline (355.630 us; speedup 1.0000x reference)
//
#include <hip/hip_runtime.h>

#define B_  8
#define L_  4096
#define DI  192
#define LOG2E 1.44269504f
#define LN2F  0.69314718f

#if __has_builtin(__builtin_amdgcn_exp2f)
#define EXP2(x) __builtin_amdgcn_exp2f(x)
#else
#define EXP2(x) __expf((x)*LN2F)
#endif

// ------------------------------ in_proj GEMM (k-major LDS, b128 reads)
__global__ __launch_bounds__(256) void k_inproj(
    const float* __restrict__ x, const float* __restrict__ w,
    float* __restrict__ xc, float* __restrict__ z)
{
  __shared__ float As[96*68];
  __shared__ float Ws[96*68];
  const int t  = threadIdx.x;
  const int m0 = blockIdx.x * 64;
  const int n0 = blockIdx.y * 64;
  for (int i = t; i < 64*24; i += 256) {
    const int row = i / 24, q = (i % 24) * 4;
    const float4 v = *(const float4*)&x[(size_t)(m0+row)*96 + q];
    As[(q+0)*68 + row] = v.x; As[(q+1)*68 + row] = v.y;
    As[(q+2)*68 + row] = v.z; As[(q+3)*68 + row] = v.w;
  }
  for (int i = t; i < 64*24; i += 256) {
    const int row = i / 24, q = (i % 24) * 4;
    const float4 v = *(const float4*)&w[(size_t)(n0+row)*96 + q];
    Ws[(q+0)*68 + row] = v.x; Ws[(q+1)*68 + row] = v.y;
    Ws[(q+2)*68 + row] = v.z; Ws[(q+3)*68 + row] = v.w;
  }
  __syncthreads();
  const int tx = t & 15, ty = t >> 4;
  float acc[4][4] = {};
#pragma unroll 4
  for (int kk = 0; kk < 96; ++kk) {
    const float4 a4 = *(const float4*)&As[kk*68 + ty*4];
    const float4 b4 = *(const float4*)&Ws[kk*68 + tx*4];
    const float a[4] = {a4.x, a4.y, a4.z, a4.w};
    const float b[4] = {b4.x, b4.y, b4.z, b4.w};
#pragma unroll
    for (int i = 0; i < 4; ++i)
#pragma unroll
      for (int j = 0; j < 4; ++j) acc[i][j] = fmaf(a[i], b[j], acc[i][j]);
  }
#pragma unroll
  for (int i = 0; i < 4; ++i) {
    const int row = m0 + ty*4 + i;
#pragma unroll
    for (int j = 0; j < 4; ++j) {
      const int col = n0 + tx*4 + j;
      if (col < DI) xc[(size_t)row*DI + col]      = acc[i][j];
      else          z [(size_t)row*DI + col - DI] = acc[i][j];
    }
  }
}

// ---------------- depthwise 3x3 conv + SiLU (sliding window)
// TR: also write transposed copy xa_T[(w<<6)|h] = xa[(h<<6)|w].
template<bool TR>
__global__ __launch_bounds__(192) void k_conv(
    const float* __restrict__ xc, const float* __restrict__ cw,
    const float* __restrict__ cb, float* __restrict__ xa,
    float* __restrict__ xa_t)
{
  const int blk = blockIdx.x;
  const int wg = blk & 3, h = (blk >> 2) & 63, b = blk >> 8;
  const int d  = threadIdx.x;
  float wreg[9];
#pragma unroll
  for (int i = 0; i < 9; ++i) wreg[i] = cw[d*9 + i];
  const float bias = cb[d];
  const float* base = xc + ((size_t)(b) << 12)*DI + d;
  const int w0 = wg * 16;
  const bool hm = (h > 0), hp = (h < 63);
  auto LD = [&](int hh, int ww, bool ok) -> float {
    return ok ? base[(size_t)((hh << 6) + ww)*DI] : 0.f;
  };
  float a0 = LD(h-1, w0-1, hm && w0 > 0);
  float a1 = LD(h,   w0-1, w0 > 0);
  float a2 = LD(h+1, w0-1, hp && w0 > 0);
  float b0 = LD(h-1, w0, hm);
  float b1 = LD(h,   w0, true);
  float b2 = LD(h+1, w0, hp);
  float* op  = xa + ((size_t)((b << 12) + (h << 6) + w0))*DI + d;
  float* opT = TR ? xa_t + ((size_t)((b << 12) + (w0 << 6) + h))*DI + d : nullptr;
#pragma unroll 4
  for (int w = w0; w < w0 + 16; ++w) {
    const bool wp = (w < 63);
    const float c0 = LD(h-1, w+1, hm && wp);
    const float c1 = LD(h,   w+1, wp);
    const float c2 = LD(h+1, w+1, hp && wp);
    float acc = bias;
    acc = fmaf(a0, wreg[0], acc); acc = fmaf(b0, wreg[1], acc); acc = fmaf(c0, wreg[2], acc);
    acc = fmaf(a1, wreg[3], acc); acc = fmaf(b1, wreg[4], acc); acc = fmaf(c1, wreg[5], acc);
    acc = fmaf(a2, wreg[6], acc); acc = fmaf(b2, wreg[7], acc); acc = fmaf(c2, wreg[8], acc);
    const float sig = 1.f / (1.f + __expf(-acc));
    const float val = acc * sig;
    *op = val;
    if (TR) { *opT = val; opT += 64*DI; }
    op += DI;
    a0 = b0; a1 = b1; a2 = b2;
    b0 = c0; b1 = c1; b2 = c2;
  }
}

// ------------------------------------- x_proj: LDS-staged weights GEMM
// TRANS: k=0/2 records at site index; k=1/3 records at swh(site) (scan order).
#define WSL(c,q) ((c)*36 + ((((q) ^ (((c)>>2)&7)) & 7) << 2))
template<bool TRANS>
__global__ __launch_bounds__(256) void k_xproj(
    const float* __restrict__ xa, const float* __restrict__ xw,
    float* __restrict__ proj)
{
  __shared__ float V[64*196];            // 50176 B
  __shared__ float W[152*36];            // 21888 B
  const int t  = threadIdx.x;
  const int s0 = blockIdx.x * 64;
  for (int i = t; i < 64*48; i += 256) {
    const int row = i / 48;
    const int q   = (i % 48) * 4;
    *(float4*)&V[row*196 + q] = *(const float4*)&xa[(size_t)(s0+row)*192 + q];
  }
  const int tx = t & 15;
  const int ty = t >> 4;
  const int c0 = tx * 10;
  float acc[4][10] = {};
#pragma unroll 1
  for (int p = 0; p < 6; ++p) {
    __syncthreads();
    for (int i = t; i < 152*8; i += 256) {
      const int c = i >> 3, q = i & 7;
      *(float4*)&W[WSL(c,q)] = *(const float4*)&xw[(size_t)c*192 + p*32 + q*4];
    }
    __syncthreads();
#pragma unroll
    for (int rs = 0; rs < 8; ++rs) {
      const int r0 = p*32 + rs*4;
      float av[4][4];
#pragma unroll
      for (int m = 0; m < 4; ++m) {
        const float4 a4 = *(const float4*)&V[(ty*4+m)*196 + r0];
        av[m][0]=a4.x; av[m][1]=a4.y; av[m][2]=a4.z; av[m][3]=a4.w;
      }
      float wr[10][4];
#pragma unroll
      for (int j = 0; j < 10; ++j) {
        const int cg = (c0 + j < 152) ? c0 + j : 151;
        const float4 w4 = *(const float4*)&W[WSL(cg,rs)];
        wr[j][0]=w4.x; wr[j][1]=w4.y; wr[j][2]=w4.z; wr[j][3]=w4.w;
      }
#pragma unroll
      for (int i = 0; i < 4; ++i)
#pragma unroll
        for (int m = 0; m < 4; ++m)
#pragma unroll
          for (int j = 0; j < 10; ++j)
            acc[m][j] = fmaf(av[m][i], wr[j][i], acc[m][j]);
    }
  }
  __syncthreads();
  float* Csm = V;                        // [64][162]
#pragma unroll
  for (int m = 0; m < 4; ++m)
#pragma unroll
    for (int j = 0; j < 10; ++j)
      if (c0 + j < 152) Csm[(ty*4+m)*162 + c0 + j] = acc[m][j];
  __syncthreads();
  const int b = s0 >> 12;
  const int sbase = s0 & 4095;
  const int hh = sbase >> 6;             // block covers one h-row
#pragma unroll 1
  for (int k = 0; k < 4; ++k) {
    const bool scat = TRANS && (k & 1);
    float* opb = proj + (size_t)((b<<2)+k)*L_*40;
#pragma unroll
    for (int it = 0; it < 10; ++it) {
      const int f = it*256 + t;          // 0..2559
      const int s = f / 40, c = f - s*40;
      const int row = scat ? ((s << 6) | hh) : (sbase + s);
      opb[(size_t)row*40 + c] = (c < 38) ? Csm[s*162 + k*38 + c] : 0.f;
    }
  }
}

// -------------------------------------------------- scan phase 1 (TRANS)
// All directions walk record/u index sequentially (stride ±1).
// k=1/3 read u from xa_T; records already in scan order.
template<int NC>
__global__ __launch_bounds__(192) void k_scan1t(
    const float* __restrict__ xa, const float* __restrict__ xa_t,
    const float* __restrict__ proj,
    const float* __restrict__ alog, const float* __restrict__ dtw,
    const float* __restrict__ dtb,
    float* __restrict__ P, float* __restrict__ Hl)
{
  constexpr int CL = L_ / NC;
  const int blk = blockIdx.x;            // b*(4*NC) + kslot*NC + c
  const int c = blk % NC, b = blk / (NC*4);
  const int k = ((blk / NC) + b) & 3;
  const int d = threadIdx.x;
  const int kd = k*DI + d;
  const int rev = (k >> 1) & 1;
  float A2[16], dw[6];
#pragma unroll
  for (int n = 0; n < 16; ++n) A2[n] = -__expf(alog[kd*16 + n]) * LOG2E;
#pragma unroll
  for (int r = 0; r < 6; ++r) dw[r] = dtw[kd*6 + r];
  const float db = dtb[kd];
  float h[16];
#pragma unroll
  for (int n = 0; n < 16; ++n) h[n] = 0.f;
  float Sd = 0.f;
  const int l0 = c * CL;
  const int idx0 = rev ? 4095 - l0 : l0;
  const int stride = rev ? -1 : 1;
  const float* usrc = (k & 1) ? xa_t : xa;
  const float* up = usrc + ((size_t)(b << 12) + idx0)*DI + d;
  const char* pr8 = (const char*)(proj + ((((size_t)((b<<2)+k)) << 12) + idx0)*40);
  const ptrdiff_t ustep = (ptrdiff_t)stride * DI;
  const ptrdiff_t pstepB = (ptrdiff_t)stride * 160;
  const size_t obase = ((size_t)((b*4 + k)*NC + c)) * 16 * DI + d;
#pragma unroll 2
  for (int t = 0; t < CL; ++t) {
    const float u = *up;
    const float4 q0 = *(const float4*)(pr8 +  0);
    const float4 q1 = *(const float4*)(pr8 + 16);
    const float4 q2 = *(const float4*)(pr8 + 32);
    const float4 q3 = *(const float4*)(pr8 + 48);
    const float4 q4 = *(const float4*)(pr8 + 64);
    const float4 q5 = *(const float4*)(pr8 + 80);
    float xdt = db;
    xdt = fmaf(dw[0], q0.x, xdt); xdt = fmaf(dw[1], q0.y, xdt);
    xdt = fmaf(dw[2], q0.z, xdt); xdt = fmaf(dw[3], q0.w, xdt);
    xdt = fmaf(dw[4], q1.x, xdt); xdt = fmaf(dw[5], q1.y, xdt);
    const float delta = (xdt > 20.f) ? xdt
                       : LN2F * __log2f(1.f + EXP2(xdt * LOG2E));
    Sd += delta;
    const float du = delta * u;
    const float Bv[16] = {q1.z,q1.w,q2.x,q2.y,q2.z,q2.w,q3.x,q3.y,
                          q3.z,q3.w,q4.x,q4.y,q4.z,q4.w,q5.x,q5.y};
#pragma unroll
    for (int n = 0; n < 16; ++n) {
      const float dA = EXP2(delta * A2[n]);
      h[n] = fmaf(dA, h[n], du * Bv[n]);
    }
    up += ustep; pr8 += pstepB;
  }
#pragma unroll
  for (int n = 0; n < 16; ++n) {
    P[obase + n*DI]  = EXP2(A2[n] * Sd);
    Hl[obase + n*DI] = h[n];
  }
}

// --------------------------------- scan phase 2: chunk combine (+opt zero)
template<int NC, bool ZERO>
__global__ __launch_bounds__(256) void k_scan2(
    const float* P, const float* __restrict__ Hl, float* hin,
    float* __restrict__ ycomb)
{
  const int tid = blockIdx.x * 256 + threadIdx.x;   // < 98304
  if (ZERO)
    for (size_t i = tid; i < (size_t)B_*L_*DI; i += 98304) ycomb[i] = 0.f;
  const int d  = tid % DI;
  const int n  = (tid / DI) & 15;
  const int bk = tid / (DI*16);                     // 0..31
  float h = 0.f;
  for (int cc = 0; cc < NC; ++cc) {
    const size_t idx = ((size_t)(bk*NC + cc)*16 + n)*DI + d;
    const float pv = P[idx];
    const float hl = Hl[idx];
    hin[idx] = h;
    h = fmaf(pv, h, hl);
  }
}

// ---------------- scan phase 3 (TRANS flat): sequential record/u walks for
// all k; y written in SITE order (k=1/3: 768B coalesced stores @64-row stride).
template<int NC>
__global__ __launch_bounds__(192) void k_scan3t(
    const float* __restrict__ xa, const float* __restrict__ xa_t,
    const float* __restrict__ proj,
    const float* __restrict__ alog, const float* __restrict__ dtw,
    const float* __restrict__ dtb, const float* __restrict__ Dv,
    const float* __restrict__ hin,
    float* __restrict__ y0, float* __restrict__ y1,
    float* __restrict__ y2, float* __restrict__ y3)
{
  constexpr int CL = L_ / NC;
  const int blk = blockIdx.x;
  const int c = blk % NC, b = blk / (NC*4);
  const int k = ((blk / NC) + b) & 3;
  const int d = threadIdx.x;
  const int kd = k*DI + d;
  const int rev = (k >> 1) & 1;
  float A2[16], dw[6];
#pragma unroll
  for (int n = 0; n < 16; ++n) A2[n] = -__expf(alog[kd*16 + n]) * LOG2E;
#pragma unroll
  for (int r = 0; r < 6; ++r) dw[r] = dtw[kd*6 + r];
  const float db = dtb[kd];
  const float Dd = Dv[kd];
  float h[16];
  const size_t base = ((size_t)((b*4 + k)*NC + c)) * 16 * DI + d;
#pragma unroll
  for (int n = 0; n < 16; ++n) h[n] = hin[base + n*DI];
  const int l0 = c * CL;
  const int idx0 = rev ? 4095 - l0 : l0;
  const int stride = rev ? -1 : 1;
  const float* usrc = (k & 1) ? xa_t : xa;
  const float* up = usrc + ((size_t)(b << 12) + idx0)*DI + d;
  const char* pr8 = (const char*)(proj + ((((size_t)((b<<2)+k)) << 12) + idx0)*40);
  const ptrdiff_t ustep = (ptrdiff_t)stride * DI;
  const ptrdiff_t pstepB = (ptrdiff_t)stride * 160;
  float* yb = (k == 0) ? y0 : (k == 1) ? y1 : (k == 2) ? y2 : y3;
  const int site0 = (k & 1) ? (((idx0 & 63) << 6) | (idx0 >> 6)) : idx0;
  float* yp = yb + ((size_t)(b << 12) + site0)*DI + d;
  const ptrdiff_t ystep = (ptrdiff_t)stride * ((k & 1) ? 64 : 1) * DI;
#pragma unroll 2
  for (int t = 0; t < CL; ++t) {
    const float u = *up;
    const float4 q0 = *(const float4*)(pr8 +   0);
    const float4 q1 = *(const float4*)(pr8 +  16);
    const float4 q2 = *(const float4*)(pr8 +  32);
    const float4 q3 = *(const float4*)(pr8 +  48);
    const float4 q4 = *(const float4*)(pr8 +  64);
    const float4 q5 = *(const float4*)(pr8 +  80);
    const float4 q6 = *(const float4*)(pr8 +  96);
    const float4 q7 = *(const float4*)(pr8 + 112);
    const float4 q8 = *(const float4*)(pr8 + 128);
    const float4 q9 = *(const float4*)(pr8 + 144);
    float xdt = db;
    xdt = fmaf(dw[0], q0.x, xdt); xdt = fmaf(dw[1], q0.y, xdt);
    xdt = fmaf(dw[2], q0.z, xdt); xdt = fmaf(dw[3], q0.w, xdt);
    xdt = fmaf(dw[4], q1.x, xdt); xdt = fmaf(dw[5], q1.y, xdt);
    const float delta = (xdt > 20.f) ? xdt
                       : LN2F * __log2f(1.f + EXP2(xdt * LOG2E));
    const float du = delta * u;
    const float Bv[16] = {q1.z,q1.w,q2.x,q2.y,q2.z,q2.w,q3.x,q3.y,
                          q3.z,q3.w,q4.x,q4.y,q4.z,q4.w,q5.x,q5.y};
    const float Cv[16] = {q5.z,q5.w,q6.x,q6.y,q6.z,q6.w,q7.x,q7.y,
                          q7.z,q7.w,q8.x,q8.y,q8.z,q8.w,q9.x,q9.y};
    float y = 0.f;
#pragma unroll
    for (int n = 0; n < 16; ++n) {
      const float dA = EXP2(delta * A2[n]);
      h[n] = fmaf(dA, h[n], du * Bv[n]);
      y = fmaf(h[n], Cv[n], y);
    }
    y = fmaf(u, Dd, y);
    *yp = y;
    yp += ystep; up += ustep; pr8 += pstepB;
  }
}

// ------------------------- scan phase 1/3 (non-trans fallback, round-15)
template<int NC>
__global__ __launch_bounds__(192) void k_scan1(
    const float* __restrict__ xa, const float* __restrict__ proj,
    const float* __restrict__ alog, const float* __restrict__ dtw,
    const float* __restrict__ dtb,
    float* __restrict__ P, float* __restrict__ Hl)
{
  constexpr int CL = L_ / NC;
  const int blk = blockIdx.x;
  const int c = blk % NC, b = blk / (NC*4);
  const int k = ((blk / NC) + b) & 3;
  const int d = threadIdx.x;
  const int kd = k*DI + d;
  const int rev = (k >> 1) & 1, sw = k & 1;
  float A2[16], dw[6];
#pragma unroll
  for (int n = 0; n < 16; ++n) A2[n] = -__expf(alog[kd*16 + n]) * LOG2E;
#pragma unroll
  for (int r = 0; r < 6; ++r) dw[r] = dtw[kd*6 + r];
  const float db = dtb[kd];
  float h[16];
#pragma unroll
  for (int n = 0; n < 16; ++n) h[n] = 0.f;
  float Sd = 0.f;
  const int l0 = c * CL;
  const int l2_0 = rev ? 4095 - l0 : l0;
  const int sbase = sw ? (((l2_0 & 63) << 6) | (l2_0 >> 6)) : l2_0;
  const int stp = sw ? (rev ? -64 : 64) : (rev ? -1 : 1);
  const float* up = xa + ((size_t)(b << 12) + sbase)*DI + d;
  const char* pr8 = (const char*)(proj + ((((size_t)((b<<2)+k)) << 12) + sbase)*40);
  const ptrdiff_t ustep = (ptrdiff_t)stp * DI;
  const ptrdiff_t pstepB = (ptrdiff_t)stp * 160;
  const size_t obase = ((size_t)((b*4 + k)*NC + c)) * 16 * DI + d;
#pragma unroll 2
  for (int t = 0; t < CL; ++t) {
    const float u = *up;
    const float4 q0 = *(const float4*)(pr8 +  0);
    const float4 q1 = *(const float4*)(pr8 + 16);
    const float4 q2 = *(const float4*)(pr8 + 32);
    const float4 q3 = *(const float4*)(pr8 + 48);
    const float4 q4 = *(const float4*)(pr8 + 64);
    const float4 q5 = *(const float4*)(pr8 + 80);
    float xdt = db;
    xdt = fmaf(dw[0], q0.x, xdt); xdt = fmaf(dw[1], q0.y, xdt);
    xdt = fmaf(dw[2], q0.z, xdt); xdt = fmaf(dw[3], q0.w, xdt);
    xdt = fmaf(dw[4], q1.x, xdt); xdt = fmaf(dw[5], q1.y, xdt);
    const float delta = (xdt > 20.f) ? xdt
                       : LN2F * __log2f(1.f + EXP2(xdt * LOG2E));
    Sd += delta;
    const float du = delta * u;
    const float Bv[16] = {q1.z,q1.w,q2.x,q2.y,q2.z,q2.w,q3.x,q3.y,
                          q3.z,q3.w,q4.x,q4.y,q4.z,q4.w,q5.x,q5.y};
#pragma unroll
    for (int n = 0; n < 16; ++n) {
      const float dA = EXP2(delta * A2[n]);
      h[n] = fmaf(dA, h[n], du * Bv[n]);
    }
    up += ustep; pr8 += pstepB;
  }
#pragma unroll
  for (int n = 0; n < 16; ++n) {
    P[obase + n*DI]  = EXP2(A2[n] * Sd);
    Hl[obase + n*DI] = h[n];
  }
}

template<int NC>
__global__ __launch_bounds__(192) void k_scan3a(
    const float* __restrict__ xa, const float* __restrict__ proj,
    const float* __restrict__ alog, const float* __restrict__ dtw,
    const float* __restrict__ dtb, const float* __restrict__ Dv,
    const float* __restrict__ hin, float* __restrict__ ycomb)
{
  constexpr int CL = L_ / NC;
  const int blk = blockIdx.x;
  const int c = blk % NC, b = blk / (NC*4);
  const int k = ((blk / NC) + b) & 3;
  const int d = threadIdx.x;
  const int kd = k*DI + d;
  const int rev = (k >> 1) & 1, sw = k & 1;
  float A2[16], dw[6];
#pragma unroll
  for (int n = 0; n < 16; ++n) A2[n] = -__expf(alog[kd*16 + n]) * LOG2E;
#pragma unroll
  for (int r = 0; r < 6; ++r) dw[r] = dtw[kd*6 + r];
  const float db = dtb[kd];
  const float Dd = Dv[kd];
  float h[16];
  const size_t base = ((size_t)((b*4 + k)*NC + c)) * 16 * DI + d;
#pragma unroll
  for (int n = 0; n < 16; ++n) h[n] = hin[base + n*DI];
  const int l0 = c * CL;
  const float* xab = xa + (size_t)(b << 12)*DI + d;
  const float* pb  = proj + (((size_t)((b<<2)+k)) << 12)*40;
#pragma unroll 2
  for (int t = 0; t < CL; ++t) {
    const int l = l0 + t;
    const int l2 = rev ? 4095 - l : l;
    const int s  = sw ? (((l2 & 63) << 6) | (l2 >> 6)) : l2;
    const float u = xab[(size_t)s*DI];
    const float* pp = pb + (size_t)s*40;
    float xdt = db;
#pragma unroll
    for (int r = 0; r < 6; ++r) xdt = fmaf(dw[r], pp[r], xdt);
    const float delta = (xdt > 20.f) ? xdt : __logf(1.f + __expf(xdt));
    const float du = delta * u;
    float y = 0.f;
#pragma unroll
    for (int n = 0; n < 16; ++n) {
      const float dA = EXP2(delta * A2[n]);
      h[n] = fmaf(dA, h[n], du * pp[6+n]);
      y = fmaf(h[n], pp[22+n], y);
    }
    y = fmaf(u, Dd, y);
    atomicAdd(&ycomb[(size_t)((b<<12) + s)*DI + d], y);
  }
}

// ----------------------------- final: LayerNorm + silu(z) gate + out_proj
// MODE 0: all four y buffers site-ordered (TRANS).  MODE 1: single ycomb.
template<int MODE>
__global__ __launch_bounds__(256) void k_final(
    const float* __restrict__ y0, const float* __restrict__ y1,
    const float* __restrict__ y2, const float* __restrict__ y3,
    const float* __restrict__ zb,
    const float* __restrict__ lng, const float* __restrict__ lnb,
    const float* __restrict__ ow, float* __restrict__ out)
{
  __shared__ float yt[192*68];           // 52224 B
  __shared__ float W2[96*36];            // 13824 B
  const int t = threadIdx.x;
  const int lane = t & 63, wv = t >> 6;
  const int g0 = blockIdx.x * 64;
  for (int si = 0; si < 16; ++si) {
    const int sl = wv*16 + si;
    const int g  = g0 + sl;
    float v[3]; float sum = 0.f, sq = 0.f;
#pragma unroll
    for (int j = 0; j < 3; ++j) {
      const int ch = lane*3 + j;
      float vv = y0[(size_t)g*DI + ch];
      if (MODE == 0)
        vv += y1[(size_t)g*DI + ch] + y2[(size_t)g*DI + ch] + y3[(size_t)g*DI + ch];
      v[j] = vv;
      sum += vv; sq = fmaf(vv, vv, sq);
    }
#pragma unroll
    for (int o = 1; o < 64; o <<= 1) { sum += __shfl_xor(sum, o); sq += __shfl_xor(sq, o); }
    const float mu = sum * (1.f/192.f);
    const float rs = rsqrtf(sq*(1.f/192.f) - mu*mu + 1e-5f);
#pragma unroll
    for (int j = 0; j < 3; ++j) {
      const int ch = lane*3 + j;
      const float zv = zb[(size_t)g*DI + ch];
      const float sz = zv / (1.f + __expf(-zv));
      yt[ch*68 + sl] = ((v[j]-mu)*rs*lng[ch] + lnb[ch]) * sz;
    }
  }
  __syncthreads();
  const int tx = t & 15, ty = t >> 4;
  const int c0 = tx*6;
  float acc[4][6] = {};
#pragma unroll 1
  for (int p = 0; p < 6; ++p) {
    if (p) __syncthreads();
    for (int i = t; i < 96*8; i += 256) {
      const int c = i >> 3, q = i & 7;
      *(float4*)&W2[WSL(c,q)] = *(const float4*)&ow[(size_t)c*192 + p*32 + q*4];
    }
    __syncthreads();
#pragma unroll
    for (int rs = 0; rs < 8; ++rs) {
      const int k4 = p*32 + rs*4;
      float4 bw[6];
#pragma unroll
      for (int j = 0; j < 6; ++j) bw[j] = *(const float4*)&W2[WSL(c0+j, rs)];
#pragma unroll
      for (int i4 = 0; i4 < 4; ++i4) {
        const float4 a4 = *(const float4*)&yt[(k4+i4)*68 + ty*4];
        const float av[4] = {a4.x, a4.y, a4.z, a4.w};
        const float bv[6] = {
          i4==0?bw[0].x:i4==1?bw[0].y:i4==2?bw[0].z:bw[0].w,
          i4==0?bw[1].x:i4==1?bw[1].y:i4==2?bw[1].z:bw[1].w,
          i4==0?bw[2].x:i4==1?bw[2].y:i4==2?bw[2].z:bw[2].w,
          i4==0?bw[3].x:i4==1?bw[3].y:i4==2?bw[3].z:bw[3].w,
          i4==0?bw[4].x:i4==1?bw[4].y:i4==2?bw[4].z:bw[4].w,
          i4==0?bw[5].x:i4==1?bw[5].y:i4==2?bw[5].z:bw[5].w };
#pragma unroll
        for (int i = 0; i < 4; ++i)
#pragma unroll
          for (int j = 0; j < 6; ++j) acc[i][j] = fmaf(av[i], bv[j], acc[i][j]);
      }
    }
  }
#pragma unroll
  for (int i = 0; i < 4; ++i) {
    const size_t row = (size_t)(g0 + ty*4 + i)*96 + c0;
#pragma unroll
    for (int j = 0; j < 6; ++j) out[row + j] = acc[i][j];
  }
}

extern "C" void kernel_launch(void* const* d_in, const int* in_sizes, int n_in,
                              void* d_out, int out_size, void* d_ws, size_t ws_size,
                              hipStream_t stream)
{
  (void)in_sizes; (void)n_in; (void)out_size;
  const float* x    = (const float*)d_in[0];
  const float* ipw  = (const float*)d_in[1];
  const float* cw   = (const float*)d_in[2];
  const float* cb   = (const float*)d_in[3];
  const float* xpw  = (const float*)d_in[4];
  const float* dpw  = (const float*)d_in[5];
  const float* dpb  = (const float*)d_in[6];
  const float* alog = (const float*)d_in[7];
  const float* Dv   = (const float*)d_in[8];
  const float* lng  = (const float*)d_in[9];
  const float* lnb  = (const float*)d_in[10];
  const float* opw  = (const float*)d_in[11];
  float* out = (float*)d_out;

  float* ws    = (float*)d_ws;
  float* xc    = ws;                  // 6291456 (recycled: y0 / ycomb)
  float* zbuf  = ws + 6291456;
  float* xa    = ws + 12582912;
  float* proj  = ws + 18874368;       // 5242880
  float* after = ws + 24117248;
  const size_t YSZ = 6291456;

  k_inproj<<<dim3(512, 6), 256, 0, stream>>>(x, ipw, xc, zbuf);

  // Tier sizes (floats):
  const size_t needA = (24117248ull + 2ull*98304*128 + 2*YSZ) * 4;  // ~247 MB: NC=128 trans
  const size_t needBt = (24117248ull + 2ull*98304*64 + 3*YSZ) * 4;  // ~222 MB: NC=64 trans (proven)
  const size_t needC = (24117248ull + 2ull*98304*64 + 2*YSZ) * 4;   // ~197 MB: NC=64 non-trans
  const size_t needD = 30408704ull * 4;                             // NC=32 atomic

  if (ws_size >= needA) {
    constexpr int NC = 128;
    float* Pb  = after;                       // 12582912 (also hin)
    float* Hlb = after + (size_t)98304*NC;    // 12582912
    float* y1  = Hlb;                         // reuse Hl after scan2
    float* y2  = Hlb + YSZ;
    float* y3  = after + 2ull*98304*NC;
    float* xaT = y3 + YSZ;
    k_conv<true><<<2048, 192, 0, stream>>>(xc, cw, cb, xa, xaT);
    k_xproj<true><<<512, 256, 0, stream>>>(xa, xpw, proj);
    k_scan1t<NC><<<8*4*NC, 192, 0, stream>>>(xa, xaT, proj, alog, dpw, dpb, Pb, Hlb);
    k_scan2<NC,false><<<384, 256, 0, stream>>>(Pb, Hlb, Pb, nullptr);
    k_scan3t<NC><<<8*4*NC, 192, 0, stream>>>(xa, xaT, proj, alog, dpw, dpb, Dv, Pb, xc, y1, y2, y3);
    k_final<0><<<512, 256, 0, stream>>>(xc, y1, y2, y3, zbuf, lng, lnb, opw, out);
  } else if (ws_size >= needBt) {
    constexpr int NC = 64;
    float* Pb  = after;                       // 6291456 (also hin)
    float* Hlb = after + (size_t)98304*NC;    // 6291456
    float* y1  = Hlb;                         // reuse Hl after scan2
    float* y2  = after + 2ull*98304*NC;
    float* y3  = y2 + YSZ;
    float* xaT = y3 + YSZ;
    k_conv<true><<<2048, 192, 0, stream>>>(xc, cw, cb, xa, xaT);
    k_xproj<true><<<512, 256, 0, stream>>>(xa, xpw, proj);
    k_scan1t<NC><<<8*4*NC, 192, 0, stream>>>(xa, xaT, proj, alog, dpw, dpb, Pb, Hlb);
    k_scan2<NC,false><<<384, 256, 0, stream>>>(Pb, Hlb, Pb, nullptr);
    k_scan3t<NC><<<8*4*NC, 192, 0, stream>>>(xa, xaT, proj, alog, dpw, dpb, Dv, Pb, xc, y1, y2, y3);
    k_final<0><<<512, 256, 0, stream>>>(xc, y1, y2, y3, zbuf, lng, lnb, opw, out);
  } else if (ws_size >= needC) {
    constexpr int NC = 64;
    float* Pb  = after;
    float* Hlb = after + (size_t)98304*NC;
    k_conv<false><<<2048, 192, 0, stream>>>(xc, cw, cb, xa, nullptr);
    k_xproj<false><<<512, 256, 0, stream>>>(xa, xpw, proj);
    k_scan1<NC><<<8*4*NC, 192, 0, stream>>>(xa, proj, alog, dpw, dpb, Pb, Hlb);
    k_scan2<NC,true><<<384, 256, 0, stream>>>(Pb, Hlb, Pb, xc);
    k_scan3a<NC><<<8*4*NC, 192, 0, stream>>>(xa, proj, alog, dpw, dpb, Dv, Pb, xc);
    k_final<1><<<512, 256, 0, stream>>>(xc, nullptr, nullptr, nullptr, zbuf, lng, lnb, opw, out);
  } else {
    constexpr int NC = 32;
    float* Pb  = after;
    float* Hlb = after + (size_t)98304*NC;
    k_conv<false><<<2048, 192, 0, stream>>>(xc, cw, cb, xa, nullptr);
    k_xproj<false><<<512, 256, 0, stream>>>(xa, xpw, proj);
    k_scan1<NC><<<8*4*NC, 192, 0, stream>>>(xa, proj, alog, dpw, dpb, Pb, Hlb);
    k_scan2<NC,true><<<384, 256, 0, stream>>>(Pb, Hlb, Pb, xc);
    k_scan3a<NC><<<8*4*NC, 192, 0, stream>>>(xa, proj, alog, dpw, dpb, Dv, Pb, xc);
    k_final<1><<<512, 256, 0, stream>>>(xc, nullptr, nullptr, nullptr, zbuf, lng, lnb, opw, out);
  }
}

// Round 17
// 336.256 us; speedup vs baseline: 1.0576x; 1.0576x over previous
//
#include <hip/hip_runtime.h>

#define B_  8
#define L_  4096
#define DI  192
#define LOG2E 1.44269504f
#define LN2F  0.69314718f

#if __has_builtin(__builtin_amdgcn_exp2f)
#define EXP2(x) __builtin_amdgcn_exp2f(x)
#else
#define EXP2(x) __expf((x)*LN2F)
#endif

// ------------------------------ in_proj GEMM (k-major LDS, b128 reads)
__global__ __launch_bounds__(256) void k_inproj(
    const float* __restrict__ x, const float* __restrict__ w,
    float* __restrict__ xc, float* __restrict__ z)
{
  __shared__ float As[96*68];            // [kk][row], stride 68
  __shared__ float Ws[96*68];
  const int t  = threadIdx.x;
  const int m0 = blockIdx.x * 64;
  const int n0 = blockIdx.y * 64;
  for (int i = t; i < 64*24; i += 256) {
    const int row = i / 24, q = (i % 24) * 4;
    const float4 v = *(const float4*)&x[(size_t)(m0+row)*96 + q];
    As[(q+0)*68 + row] = v.x; As[(q+1)*68 + row] = v.y;
    As[(q+2)*68 + row] = v.z; As[(q+3)*68 + row] = v.w;
  }
  for (int i = t; i < 64*24; i += 256) {
    const int row = i / 24, q = (i % 24) * 4;
    const float4 v = *(const float4*)&w[(size_t)(n0+row)*96 + q];
    Ws[(q+0)*68 + row] = v.x; Ws[(q+1)*68 + row] = v.y;
    Ws[(q+2)*68 + row] = v.z; Ws[(q+3)*68 + row] = v.w;
  }
  __syncthreads();
  const int tx = t & 15, ty = t >> 4;
  float acc[4][4] = {};
#pragma unroll 4
  for (int kk = 0; kk < 96; ++kk) {
    const float4 a4 = *(const float4*)&As[kk*68 + ty*4];
    const float4 b4 = *(const float4*)&Ws[kk*68 + tx*4];
    const float a[4] = {a4.x, a4.y, a4.z, a4.w};
    const float b[4] = {b4.x, b4.y, b4.z, b4.w};
#pragma unroll
    for (int i = 0; i < 4; ++i)
#pragma unroll
      for (int j = 0; j < 4; ++j) acc[i][j] = fmaf(a[i], b[j], acc[i][j]);
  }
#pragma unroll
  for (int i = 0; i < 4; ++i) {
    const int row = m0 + ty*4 + i;
#pragma unroll
    for (int j = 0; j < 4; ++j) {
      const int col = n0 + tx*4 + j;
      if (col < DI) xc[(size_t)row*DI + col]      = acc[i][j];
      else          z [(size_t)row*DI + col - DI] = acc[i][j];
    }
  }
}

// ---------------- depthwise 3x3 conv + SiLU (sliding 3x3 register window)
__global__ __launch_bounds__(192) void k_conv(
    const float* __restrict__ xc, const float* __restrict__ cw,
    const float* __restrict__ cb, float* __restrict__ xa)
{
  const int blk = blockIdx.x;
  const int wg = blk & 3, h = (blk >> 2) & 63, b = blk >> 8;
  const int d  = threadIdx.x;
  float wreg[9];
#pragma unroll
  for (int i = 0; i < 9; ++i) wreg[i] = cw[d*9 + i];
  const float bias = cb[d];
  const float* base = xc + ((size_t)(b) << 12)*DI + d;
  const int w0 = wg * 16;
  const bool hm = (h > 0), hp = (h < 63);
  auto LD = [&](int hh, int ww, bool ok) -> float {
    return ok ? base[(size_t)((hh << 6) + ww)*DI] : 0.f;
  };
  float a0 = LD(h-1, w0-1, hm && w0 > 0);
  float a1 = LD(h,   w0-1, w0 > 0);
  float a2 = LD(h+1, w0-1, hp && w0 > 0);
  float b0 = LD(h-1, w0, hm);
  float b1 = LD(h,   w0, true);
  float b2 = LD(h+1, w0, hp);
  float* op = xa + ((size_t)((b << 12) + (h << 6) + w0))*DI + d;
#pragma unroll 4
  for (int w = w0; w < w0 + 16; ++w) {
    const bool wp = (w < 63);
    const float c0 = LD(h-1, w+1, hm && wp);
    const float c1 = LD(h,   w+1, wp);
    const float c2 = LD(h+1, w+1, hp && wp);
    float acc = bias;
    acc = fmaf(a0, wreg[0], acc); acc = fmaf(b0, wreg[1], acc); acc = fmaf(c0, wreg[2], acc);
    acc = fmaf(a1, wreg[3], acc); acc = fmaf(b1, wreg[4], acc); acc = fmaf(c1, wreg[5], acc);
    acc = fmaf(a2, wreg[6], acc); acc = fmaf(b2, wreg[7], acc); acc = fmaf(c2, wreg[8], acc);
    const float sig = 1.f / (1.f + __expf(-acc));
    *op = acc * sig;
    op += DI;
    a0 = b0; a1 = b1; a2 = b2;
    b0 = c0; b1 = c1; b2 = c2;
  }
}

// ------------------------------------- x_proj: LDS-staged weights GEMM
// proj SITE-major: proj[b][k][site][40] ([dt0..5|B0..15|C0..15|pad2]).
#define WSL(c,q) ((c)*36 + ((((q) ^ (((c)>>2)&7)) & 7) << 2))
__global__ __launch_bounds__(256) void k_xproj(
    const float* __restrict__ xa, const float* __restrict__ xw,
    float* __restrict__ proj)
{
  __shared__ float V[64*196];            // 50176 B
  __shared__ float W[152*36];            // 21888 B  (total 72 KB -> 2 blk/CU)
  const int t  = threadIdx.x;
  const int s0 = blockIdx.x * 64;
  for (int i = t; i < 64*48; i += 256) {
    const int row = i / 48;              // site
    const int q   = (i % 48) * 4;        // r
    *(float4*)&V[row*196 + q] = *(const float4*)&xa[(size_t)(s0+row)*192 + q];
  }
  const int tx = t & 15;                 // output group c0 = tx*10
  const int ty = t >> 4;                 // sites ty*4..+3
  const int c0 = tx * 10;
  float acc[4][10] = {};
#pragma unroll 1
  for (int p = 0; p < 6; ++p) {
    __syncthreads();                     // W free (prev panel consumed)
    for (int i = t; i < 152*8; i += 256) {
      const int c = i >> 3, q = i & 7;
      *(float4*)&W[WSL(c,q)] = *(const float4*)&xw[(size_t)c*192 + p*32 + q*4];
    }
    __syncthreads();                     // panel ready
#pragma unroll
    for (int rs = 0; rs < 8; ++rs) {
      const int r0 = p*32 + rs*4;        // global r (V index)
      float av[4][4];
#pragma unroll
      for (int m = 0; m < 4; ++m) {
        const float4 a4 = *(const float4*)&V[(ty*4+m)*196 + r0];
        av[m][0]=a4.x; av[m][1]=a4.y; av[m][2]=a4.z; av[m][3]=a4.w;
      }
      float wr[10][4];
#pragma unroll
      for (int j = 0; j < 10; ++j) {
        const int cg = (c0 + j < 152) ? c0 + j : 151;
        const float4 w4 = *(const float4*)&W[WSL(cg,rs)];
        wr[j][0]=w4.x; wr[j][1]=w4.y; wr[j][2]=w4.z; wr[j][3]=w4.w;
      }
#pragma unroll
      for (int i = 0; i < 4; ++i)
#pragma unroll
        for (int m = 0; m < 4; ++m)
#pragma unroll
          for (int j = 0; j < 10; ++j)
            acc[m][j] = fmaf(av[m][i], wr[j][i], acc[m][j]);
    }
  }
  __syncthreads();                       // V reads done; reuse as C staging
  float* Csm = V;                        // [64][162] = 10368 floats
#pragma unroll
  for (int m = 0; m < 4; ++m)
#pragma unroll
    for (int j = 0; j < 10; ++j)
      if (c0 + j < 152) Csm[(ty*4+m)*162 + c0 + j] = acc[m][j];
  __syncthreads();
  const int b = s0 >> 12;
  const int sbase = s0 & 4095;
#pragma unroll 1
  for (int k = 0; k < 4; ++k) {
    float* op = proj + ((size_t)((b<<2)+k)*L_ + sbase)*40;
#pragma unroll
    for (int it = 0; it < 10; ++it) {
      const int f = it*256 + t;          // 0..2559
      const int s = f / 40, c = f - s*40;
      op[f] = (c < 38) ? Csm[s*162 + k*38 + c] : 0.f;
    }
  }
}

// -------------------------------------------------- scan phase 1: local scan
template<int NC>
__global__ __launch_bounds__(192) void k_scan1(
    const float* __restrict__ xa, const float* __restrict__ proj,
    const float* __restrict__ alog, const float* __restrict__ dtw,
    const float* __restrict__ dtb,
    float* __restrict__ P, float* __restrict__ Hl)
{
  constexpr int CL = L_ / NC;
  const int blk = blockIdx.x;            // b*(4*NC) + k*NC + c
  const int c = blk % NC, k = (blk / NC) & 3, b = blk / (NC*4);
  const int d = threadIdx.x;
  const int kd = k*DI + d;
  const int rev = (k >> 1) & 1, sw = k & 1;
  float A2[16], dw[6];
#pragma unroll
  for (int n = 0; n < 16; ++n) A2[n] = -__expf(alog[kd*16 + n]) * LOG2E;
#pragma unroll
  for (int r = 0; r < 6; ++r) dw[r] = dtw[kd*6 + r];
  const float db = dtb[kd];
  float h[16];
#pragma unroll
  for (int n = 0; n < 16; ++n) h[n] = 0.f;
  float Sd = 0.f;
  const int l0 = c * CL;
  const int l2_0 = rev ? 4095 - l0 : l0;
  const int sbase = sw ? (((l2_0 & 63) << 6) | (l2_0 >> 6)) : l2_0;
  const int stp = sw ? (rev ? -64 : 64) : (rev ? -1 : 1);
  const float* up = xa + ((size_t)(b << 12) + sbase)*DI + d;
  const char* pr8 = (const char*)(proj + ((((size_t)((b<<2)+k)) << 12) + sbase)*40);
  const ptrdiff_t ustep = (ptrdiff_t)stp * DI;
  const ptrdiff_t pstepB = (ptrdiff_t)stp * 160;
#pragma unroll 4
  for (int t = 0; t < CL; ++t) {
    const float u = *up;
    const float4 q0 = *(const float4*)(pr8 +  0);
    const float4 q1 = *(const float4*)(pr8 + 16);
    const float4 q2 = *(const float4*)(pr8 + 32);
    const float4 q3 = *(const float4*)(pr8 + 48);
    const float4 q4 = *(const float4*)(pr8 + 64);
    const float4 q5 = *(const float4*)(pr8 + 80);
    float xdt = db;
    xdt = fmaf(dw[0], q0.x, xdt); xdt = fmaf(dw[1], q0.y, xdt);
    xdt = fmaf(dw[2], q0.z, xdt); xdt = fmaf(dw[3], q0.w, xdt);
    xdt = fmaf(dw[4], q1.x, xdt); xdt = fmaf(dw[5], q1.y, xdt);
    const float delta = (xdt > 20.f) ? xdt
                       : LN2F * __log2f(1.f + EXP2(xdt * LOG2E));
    Sd += delta;
    const float du = delta * u;
    const float Bv[16] = {q1.z,q1.w,q2.x,q2.y,q2.z,q2.w,q3.x,q3.y,
                          q3.z,q3.w,q4.x,q4.y,q4.z,q4.w,q5.x,q5.y};
#pragma unroll
    for (int n = 0; n < 16; ++n) {
      const float dA = EXP2(delta * A2[n]);
      h[n] = fmaf(dA, h[n], du * Bv[n]);
    }
    up += ustep; pr8 += pstepB;
  }
  const size_t base = (size_t)blk * 16 * DI + d;
#pragma unroll
  for (int n = 0; n < 16; ++n) {
    P[base + n*DI]  = EXP2(A2[n] * Sd);
    Hl[base + n*DI] = h[n];
  }
}

// --------------------------------- scan phase 2: chunk combine (+opt zero)
// hin MAY alias P (reads P[idx]/Hl[idx] strictly before writing hin[idx]).
template<int NC, bool ZERO>
__global__ __launch_bounds__(256) void k_scan2(
    const float* P, const float* __restrict__ Hl, float* hin,
    float* __restrict__ ycomb)
{
  const int tid = blockIdx.x * 256 + threadIdx.x;   // < 98304
  if (ZERO)
    for (size_t i = tid; i < (size_t)B_*L_*DI; i += 98304) ycomb[i] = 0.f;
  const int d  = tid % DI;
  const int n  = (tid / DI) & 15;
  const int bk = tid / (DI*16);                     // 0..31
  float h = 0.f;
  for (int cc = 0; cc < NC; ++cc) {
    const size_t idx = ((size_t)(bk*NC + cc)*16 + n)*DI + d;
    const float pv = P[idx];
    const float hl = Hl[idx];
    hin[idx] = h;
    h = fmaf(pv, h, hl);
  }
}

// ---------------- scan phase 3 (flat): one (b,k,chunk) per 192-thread block,
// no LDS, no atomics. Each direction k writes its OWN buffer (row = l2,
// coalesced); k_final merges the 4 buffers.
template<int NC>
__global__ __launch_bounds__(192) void k_scan3f(
    const float* __restrict__ xa, const float* __restrict__ proj,
    const float* __restrict__ alog, const float* __restrict__ dtw,
    const float* __restrict__ dtb, const float* __restrict__ Dv,
    const float* __restrict__ hin,
    float* __restrict__ y0, float* __restrict__ y1,
    float* __restrict__ y2, float* __restrict__ y3)
{
  constexpr int CL = L_ / NC;
  const int blk = blockIdx.x;            // b*(4*NC) + k*NC + c
  const int c = blk % NC, k = (blk / NC) & 3, b = blk / (NC*4);
  const int d = threadIdx.x;
  const int kd = k*DI + d;
  const int rev = (k >> 1) & 1, sw = k & 1;
  float A2[16], dw[6];
#pragma unroll
  for (int n = 0; n < 16; ++n) A2[n] = -__expf(alog[kd*16 + n]) * LOG2E;
#pragma unroll
  for (int r = 0; r < 6; ++r) dw[r] = dtw[kd*6 + r];
  const float db = dtb[kd];
  const float Dd = Dv[kd];
  float h[16];
  const size_t base = (size_t)blk * 16 * DI + d;
#pragma unroll
  for (int n = 0; n < 16; ++n) h[n] = hin[base + n*DI];
  const int l0 = c * CL;
  const int l2_0 = rev ? 4095 - l0 : l0;
  const int sbase = sw ? (((l2_0 & 63) << 6) | (l2_0 >> 6)) : l2_0;
  const int stp = sw ? (rev ? -64 : 64) : (rev ? -1 : 1);
  const float* up = xa + ((size_t)(b << 12) + sbase)*DI + d;
  const char* pr8 = (const char*)(proj + ((((size_t)((b<<2)+k)) << 12) + sbase)*40);
  const ptrdiff_t ustep = (ptrdiff_t)stp * DI;
  const ptrdiff_t pstepB = (ptrdiff_t)stp * 160;
  float* yb = (k == 0) ? y0 : (k == 1) ? y1 : (k == 2) ? y2 : y3;
  float* yp = yb + ((size_t)(b << 12) + l2_0)*DI + d;
  const ptrdiff_t ystep = (ptrdiff_t)(rev ? -1 : 1) * DI;
#pragma unroll 4
  for (int t = 0; t < CL; ++t) {
    const float u = *up;
    const float4 q0 = *(const float4*)(pr8 +   0);
    const float4 q1 = *(const float4*)(pr8 +  16);
    const float4 q2 = *(const float4*)(pr8 +  32);
    const float4 q3 = *(const float4*)(pr8 +  48);
    const float4 q4 = *(const float4*)(pr8 +  64);
    const float4 q5 = *(const float4*)(pr8 +  80);
    const float4 q6 = *(const float4*)(pr8 +  96);
    const float4 q7 = *(const float4*)(pr8 + 112);
    const float4 q8 = *(const float4*)(pr8 + 128);
    const float4 q9 = *(const float4*)(pr8 + 144);
    float xdt = db;
    xdt = fmaf(dw[0], q0.x, xdt); xdt = fmaf(dw[1], q0.y, xdt);
    xdt = fmaf(dw[2], q0.z, xdt); xdt = fmaf(dw[3], q0.w, xdt);
    xdt = fmaf(dw[4], q1.x, xdt); xdt = fmaf(dw[5], q1.y, xdt);
    const float delta = (xdt > 20.f) ? xdt
                       : LN2F * __log2f(1.f + EXP2(xdt * LOG2E));
    const float du = delta * u;
    const float Bv[16] = {q1.z,q1.w,q2.x,q2.y,q2.z,q2.w,q3.x,q3.y,
                          q3.z,q3.w,q4.x,q4.y,q4.z,q4.w,q5.x,q5.y};
    const float Cv[16] = {q5.z,q5.w,q6.x,q6.y,q6.z,q6.w,q7.x,q7.y,
                          q7.z,q7.w,q8.x,q8.y,q8.z,q8.w,q9.x,q9.y};
    float y = 0.f;
#pragma unroll
    for (int n = 0; n < 16; ++n) {
      const float dA = EXP2(delta * A2[n]);
      h[n] = fmaf(dA, h[n], du * Bv[n]);
      y = fmaf(h[n], Cv[n], y);
    }
    y = fmaf(u, Dd, y);
    *yp = y;
    yp += ystep; up += ustep; pr8 += pstepB;
  }
}

// ------------------------- scan phase 3 (atomic fallback)
template<int NC>
__global__ __launch_bounds__(192) void k_scan3a(
    const float* __restrict__ xa, const float* __restrict__ proj,
    const float* __restrict__ alog, const float* __restrict__ dtw,
    const float* __restrict__ dtb, const float* __restrict__ Dv,
    const float* __restrict__ hin, float* __restrict__ ycomb)
{
  constexpr int CL = L_ / NC;
  const int blk = blockIdx.x;
  const int c = blk % NC, k = (blk / NC) & 3, b = blk / (NC*4);
  const int d = threadIdx.x;
  const int kd = k*DI + d;
  const int rev = (k >> 1) & 1, sw = k & 1;
  float A2[16], dw[6];
#pragma unroll
  for (int n = 0; n < 16; ++n) A2[n] = -__expf(alog[kd*16 + n]) * LOG2E;
#pragma unroll
  for (int r = 0; r < 6; ++r) dw[r] = dtw[kd*6 + r];
  const float db = dtb[kd];
  const float Dd = Dv[kd];
  float h[16];
  const size_t base = (size_t)blk * 16 * DI + d;
#pragma unroll
  for (int n = 0; n < 16; ++n) h[n] = hin[base + n*DI];
  const int l0 = c * CL;
  const float* xab = xa + (size_t)(b << 12)*DI + d;
  const float* pb  = proj + (((size_t)((b<<2)+k)) << 12)*40;
#pragma unroll 2
  for (int t = 0; t < CL; ++t) {
    const int l = l0 + t;
    const int l2 = rev ? 4095 - l : l;
    const int s  = sw ? (((l2 & 63) << 6) | (l2 >> 6)) : l2;
    const float u = xab[(size_t)s*DI];
    const float* pp = pb + (size_t)s*40;
    float xdt = db;
#pragma unroll
    for (int r = 0; r < 6; ++r) xdt = fmaf(dw[r], pp[r], xdt);
    const float delta = (xdt > 20.f) ? xdt : __logf(1.f + __expf(xdt));
    const float du = delta * u;
    float y = 0.f;
#pragma unroll
    for (int n = 0; n < 16; ++n) {
      const float dA = EXP2(delta * A2[n]);
      h[n] = fmaf(dA, h[n], du * pp[6+n]);
      y = fmaf(h[n], pp[22+n], y);
    }
    y = fmaf(u, Dd, y);
    atomicAdd(&ycomb[(size_t)((b<<12) + s)*DI + d], y);
  }
}

// ----------------------------- final: LayerNorm + silu(z) gate + out_proj
// MODE 0: y = y0[g]+y2[g]+y1[r13]+y3[r13].  MODE 1: y = y0[g] (ycomb).
// out_proj weights staged in LDS panels (zero VMEM in GEMM loop).
template<int MODE>
__global__ __launch_bounds__(256) void k_final(
    const float* __restrict__ y0, const float* __restrict__ y1,
    const float* __restrict__ y2, const float* __restrict__ y3,
    const float* __restrict__ zb,
    const float* __restrict__ lng, const float* __restrict__ lnb,
    const float* __restrict__ ow, float* __restrict__ out)
{
  __shared__ float yt[192*68];           // 52224 B
  __shared__ float W2[96*36];            // 13824 B (total 66 KB -> 2 blk/CU)
  const int t = threadIdx.x;
  const int lane = t & 63, wv = t >> 6;
  const int g0 = blockIdx.x * 64;
  for (int si = 0; si < 16; ++si) {
    const int sl = wv*16 + si;
    const int g  = g0 + sl;
    const int s  = g & 4095;
    const size_t r13 = (size_t)(g & ~4095) | (((s & 63) << 6) | (s >> 6));
    float v[3]; float sum = 0.f, sq = 0.f;
#pragma unroll
    for (int j = 0; j < 3; ++j) {
      const int ch = lane*3 + j;
      float vv = y0[(size_t)g*DI + ch];
      if (MODE == 0)
        vv += y2[(size_t)g*DI + ch] + y1[r13*DI + ch] + y3[r13*DI + ch];
      v[j] = vv;
      sum += vv; sq = fmaf(vv, vv, sq);
    }
#pragma unroll
    for (int o = 1; o < 64; o <<= 1) { sum += __shfl_xor(sum, o); sq += __shfl_xor(sq, o); }
    const float mu = sum * (1.f/192.f);
    const float rs = rsqrtf(sq*(1.f/192.f) - mu*mu + 1e-5f);
#pragma unroll
    for (int j = 0; j < 3; ++j) {
      const int ch = lane*3 + j;
      const float zv = zb[(size_t)g*DI + ch];
      const float sz = zv / (1.f + __expf(-zv));
      yt[ch*68 + sl] = ((v[j]-mu)*rs*lng[ch] + lnb[ch]) * sz;
    }
  }
  __syncthreads();
  const int tx = t & 15, ty = t >> 4;
  const int c0 = tx*6;
  float acc[4][6] = {};
#pragma unroll 1
  for (int p = 0; p < 6; ++p) {
    if (p) __syncthreads();              // W2 free (prev panel consumed)
    for (int i = t; i < 96*8; i += 256) {
      const int c = i >> 3, q = i & 7;
      *(float4*)&W2[WSL(c,q)] = *(const float4*)&ow[(size_t)c*192 + p*32 + q*4];
    }
    __syncthreads();                     // panel ready
#pragma unroll
    for (int rs = 0; rs < 8; ++rs) {
      const int k4 = p*32 + rs*4;
      float4 bw[6];
#pragma unroll
      for (int j = 0; j < 6; ++j) bw[j] = *(const float4*)&W2[WSL(c0+j, rs)];
#pragma unroll
      for (int i4 = 0; i4 < 4; ++i4) {
        const float4 a4 = *(const float4*)&yt[(k4+i4)*68 + ty*4];
        const float av[4] = {a4.x, a4.y, a4.z, a4.w};
        const float bv[6] = {
          i4==0?bw[0].x:i4==1?bw[0].y:i4==2?bw[0].z:bw[0].w,
          i4==0?bw[1].x:i4==1?bw[1].y:i4==2?bw[1].z:bw[1].w,
          i4==0?bw[2].x:i4==1?bw[2].y:i4==2?bw[2].z:bw[2].w,
          i4==0?bw[3].x:i4==1?bw[3].y:i4==2?bw[3].z:bw[3].w,
          i4==0?bw[4].x:i4==1?bw[4].y:i4==2?bw[4].z:bw[4].w,
          i4==0?bw[5].x:i4==1?bw[5].y:i4==2?bw[5].z:bw[5].w };
#pragma unroll
        for (int i = 0; i < 4; ++i)
#pragma unroll
          for (int j = 0; j < 6; ++j) acc[i][j] = fmaf(av[i], bv[j], acc[i][j]);
      }
    }
  }
#pragma unroll
  for (int i = 0; i < 4; ++i) {
    const size_t row = (size_t)(g0 + ty*4 + i)*96 + c0;
#pragma unroll
    for (int j = 0; j < 6; ++j) out[row + j] = acc[i][j];
  }
}

extern "C" void kernel_launch(void* const* d_in, const int* in_sizes, int n_in,
                              void* d_out, int out_size, void* d_ws, size_t ws_size,
                              hipStream_t stream)
{
  (void)in_sizes; (void)n_in; (void)out_size;
  const float* x    = (const float*)d_in[0];
  const float* ipw  = (const float*)d_in[1];
  const float* cw   = (const float*)d_in[2];
  const float* cb   = (const float*)d_in[3];
  const float* xpw  = (const float*)d_in[4];
  const float* dpw  = (const float*)d_in[5];
  const float* dpb  = (const float*)d_in[6];
  const float* alog = (const float*)d_in[7];
  const float* Dv   = (const float*)d_in[8];
  const float* lng  = (const float*)d_in[9];
  const float* lnb  = (const float*)d_in[10];
  const float* opw  = (const float*)d_in[11];
  float* out = (float*)d_out;

  float* ws    = (float*)d_ws;
  float* xc    = ws;                  // 6291456 (recycled: y0 / ycomb)
  float* zbuf  = ws + 6291456;        // 6291456
  float* xa    = ws + 12582912;       // 6291456
  float* proj  = ws + 18874368;       // 5242880  (site-major records)
  float* after = ws + 24117248;       // scan scratch region
  const size_t YSZ = 6291456;         // one y buffer (B*L*DI floats)

  k_inproj<<<dim3(512, 6), 256, 0, stream>>>(x, ipw, xc, zbuf);
  k_conv  <<<2048, 192, 0, stream>>>(xc, cw, cb, xa);
  k_xproj <<<512, 256, 0, stream>>>(xa, xpw, proj);

  // flat tier (preferred): NC=64 -> 2048 blocks = exactly 8 blocks/CU.
  const size_t needF64  = (24117248ull + 2ull*98304*64  + 2*YSZ) * 4;// ~197 MB
  const size_t needB    = 30408704ull * 4;                           // NC32 atomic

  if (ws_size >= needF64) {
    constexpr int NC = 64;
    float* Pb  = after;                       // 6291456 (also hin)
    float* Hlb = after + (size_t)98304*NC;    // 6291456
    float* y1  = Hlb;                         // reuses Hl after scan2
    float* y2  = after + 2ull*98304*NC;
    float* y3  = y2 + YSZ;
    k_scan1<NC><<<8*4*NC, 192, 0, stream>>>(xa, proj, alog, dpw, dpb, Pb, Hlb);
    k_scan2<NC,false><<<384, 256, 0, stream>>>(Pb, Hlb, Pb, nullptr);
    k_scan3f<NC><<<8*4*NC, 192, 0, stream>>>(xa, proj, alog, dpw, dpb, Dv, Pb, xc, y1, y2, y3);
    k_final<0><<<512, 256, 0, stream>>>(xc, y1, y2, y3, zbuf, lng, lnb, opw, out);
  } else if (ws_size >= needB) {
    constexpr int NC = 32;
    float* Pb  = after;
    float* Hlb = after + (size_t)98304*NC;
    k_scan1<NC><<<8*4*NC, 192, 0, stream>>>(xa, proj, alog, dpw, dpb, Pb, Hlb);
    k_scan2<NC,true><<<384, 256, 0, stream>>>(Pb, Hlb, Pb, xc);
    k_scan3a<NC><<<8*4*NC, 192, 0, stream>>>(xa, proj, alog, dpw, dpb, Dv, Pb, xc);
    k_final<1><<<512, 256, 0, stream>>>(xc, nullptr, nullptr, nullptr, zbuf, lng, lnb, opw, out);
  } else {
    constexpr int NC = 16;
    float* Pb  = after;
    float* Hlb = after + (size_t)98304*NC;
    k_scan1<NC><<<8*4*NC, 192, 0, stream>>>(xa, proj, alog, dpw, dpb, Pb, Hlb);
    k_scan2<NC,true><<<384, 256, 0, stream>>>(Pb, Hlb, Pb, xc);
    k_scan3a<NC><<<8*4*NC, 192, 0, stream>>>(xa, proj, alog, dpw, dpb, Dv, Pb, xc);
    k_final<1><<<512, 256, 0, stream>>>(xc, nullptr, nullptr, nullptr, zbuf, lng, lnb, opw, out);
  }
}